// Round 14
// baseline (1083.524 us; speedup 1.0000x reference)
//
#include <hip/hip_runtime.h>
#include <math.h>

#define N_NODES 50000
#define M_PAD   50048   // 391 * 128
#define N_EDGES 800000
#define HID 512

typedef short bf16x8 __attribute__((ext_vector_type(8)));
typedef float f32x4  __attribute__((ext_vector_type(4)));
typedef unsigned short u16x4 __attribute__((ext_vector_type(4)));
typedef unsigned short u16x8 __attribute__((ext_vector_type(8)));

__device__ inline float b2f(unsigned short u) {
    union { unsigned int i; float f; } v; v.i = ((unsigned int)u) << 16; return v.f;
}
__device__ inline unsigned short f2b(float f) {
    union { float f; unsigned int i; } v; v.f = f;
    unsigned int r = v.i + 0x7FFFu + ((v.i >> 16) & 1u);
    return (unsigned short)(r >> 16);
}

// ---------------- CSR build ----------------

// zero counts/cursor; block 0 thread 0 also detects int64-vs-int32 edge layout
__global__ void zero_detect_kernel(int* __restrict__ p, int n,
                                   const int* __restrict__ e, int* __restrict__ flag) {
    int i = blockIdx.x * blockDim.x + threadIdx.x;
    if (i < n) p[i] = 0;
    if (blockIdx.x == 0 && threadIdx.x == 0) {
        int is64 = 1;
        for (int k = 0; k < 16; ++k)
            if (e[2 * k + 1] != 0) is64 = 0;
        *flag = is64;
    }
}

__global__ void hist_kernel(const void* __restrict__ eidx, const int* __restrict__ flag,
                            int* __restrict__ counts) {
    int e = blockIdx.x * blockDim.x + threadIdx.x;
    if (e >= N_EDGES) return;
    int is64 = *flag;
    int d;
    if (is64) d = (int)((const long long*)eidx)[N_EDGES + e];
    else      d = ((const int*)eidx)[N_EDGES + e];
    atomicAdd(&counts[d], 1);
}

__global__ __launch_bounds__(1024) void scan_kernel(const int* __restrict__ counts,
                                                    int* __restrict__ offsets) {
    __shared__ int sums[1024];
    int t = threadIdx.x;
    const int CH = (N_NODES + 1023) / 1024;  // 49
    int lo = t * CH;
    int hi = min(lo + CH, N_NODES);
    int s = 0;
    for (int i = lo; i < hi; ++i) s += counts[i];
    sums[t] = s;
    __syncthreads();
    for (int off = 1; off < 1024; off <<= 1) {
        int v = 0;
        if (t >= off) v = sums[t - off];
        __syncthreads();
        sums[t] += v;
        __syncthreads();
    }
    int excl = (t == 0) ? 0 : sums[t - 1];
    for (int i = lo; i < hi; ++i) { offsets[i] = excl; excl += counts[i]; }
    if (t == 1023) offsets[N_NODES] = excl;
}

__global__ void fill_kernel(const void* __restrict__ eidx, const int* __restrict__ flag,
                            const int* __restrict__ offsets, int* __restrict__ cursor,
                            int* __restrict__ edge_src) {
    int e = blockIdx.x * blockDim.x + threadIdx.x;
    if (e >= N_EDGES) return;
    int is64 = *flag;
    int s, d;
    if (is64) {
        const long long* p = (const long long*)eidx;
        s = (int)p[e];
        d = (int)p[N_EDGES + e];
    } else {
        const int* p = (const int*)eidx;
        s = p[e];
        d = p[N_EDGES + e];
    }
    int pos = atomicAdd(&cursor[d], 1);
    edge_src[offsets[d] + pos] = s;
}

// ---------------- conversions ----------------

// x (f32 [N,256]) -> bf16 featB1 [M_PAD][256], pad rows zeroed
__global__ __launch_bounds__(256) void xconv_kernel(const float* __restrict__ x,
                                                    unsigned short* __restrict__ feat) {
    int id = blockIdx.x * 256 + threadIdx.x;
    if (id >= M_PAD * 64) return;
    int row = id >> 6;
    int c = (id & 63) * 4;
    float4 v = make_float4(0.f, 0.f, 0.f, 0.f);
    if (row < N_NODES) v = *(const float4*)(x + (size_t)row * 256 + c);
    ushort4 h;
    h.x = f2b(v.x); h.y = f2b(v.y); h.z = f2b(v.z); h.w = f2b(v.w);
    *(ushort4*)(feat + (size_t)row * 256 + c) = h;
}

// all 6 weights transposed in ONE launch: grid (512, 6)
__global__ __launch_bounds__(128) void wconv_all_kernel(
    const float* __restrict__ Wl0, const float* __restrict__ Wr0,
    const float* __restrict__ Wl1, const float* __restrict__ Wr1,
    const float* __restrict__ Wl2, const float* __restrict__ Wr2,
    unsigned short* __restrict__ Tl0, unsigned short* __restrict__ Tr0,
    unsigned short* __restrict__ Tl1, unsigned short* __restrict__ Tr1,
    unsigned short* __restrict__ Tl2, unsigned short* __restrict__ Tr2) {
    const int y = blockIdx.y;
    const float* W = (y == 0) ? Wl0 : (y == 1) ? Wr0 : (y == 2) ? Wl1
                   : (y == 3) ? Wr1 : (y == 4) ? Wl2 : Wr2;
    unsigned short* T = (y == 0) ? Tl0 : (y == 1) ? Tr0 : (y == 2) ? Tl1
                      : (y == 3) ? Tr1 : (y == 4) ? Tl2 : Tr2;
    const int K = (y < 2) ? 256 : 512;
    int n = blockIdx.x;  // 0..511
    for (int k = threadIdx.x; k < K; k += 128)
        T[(size_t)n * K + k] = f2b(W[(size_t)k * HID + n]);
}

// ---------------- FAT kernel: [P = feat@W2t] blocks + [gather] blocks ----------------
// Blocks < NP (=782): 2-phase 128x256 MFMA GEMM computing P = feat @ W2t^T (bf16,
//   no bias) — the R13-verified structure with bijective XCD-pair swizzle.
// Blocks >= NP: 8-nodes-per-block row-gather (R8/R13-verified 4-chain), agg <- sum
//   feat[src].  Both roles depend only on `feat`, so the MFMA work of P rides in
//   the fabric-bound gather's compute shadow.
// DIN = feat width (256 layer 1, 512 layers 2-3).  feat/agg/P strides = DIN/DIN/512.

template <int DIN>
__global__ __launch_bounds__(512, 2) void fat_kernel(
    const unsigned short* __restrict__ feat, const unsigned short* __restrict__ W2t,
    unsigned short* __restrict__ P,
    const int* __restrict__ off, const int* __restrict__ esrc,
    unsigned short* __restrict__ agg, int NP) {
    __shared__ unsigned short S[2 * 12288];  // 2 x (A 4096 + B 8192) u16 = 48 KB
    const int tid = threadIdx.x;

    if ((int)blockIdx.x < NP) {
        // ---- GEMM role: P[M][512] = feat[M][DIN] @ W2t[512][DIN]^T ----
        const int T = NP;                 // 782
        const int q = T >> 3, r = T & 7;
        const int xcd = blockIdx.x & 7;
        const int n0 = blockIdx.x >> 3;
        const int g = xcd * q + min(xcd, r) + n0;
        const int bm = (g >> 1) * 128;
        const int bn = (g & 1) * 256;

        const int l = tid & 63;
        const int w = tid >> 6;
        const int wr = (w >> 2) * 64;
        const int wc = (w & 3) * 64;

        const int se = (tid >> 2) * 32 + (tid & 3) * 8;
        const unsigned short* gA  = feat + (size_t)(bm + (tid >> 2)) * DIN + (tid & 3) * 8;
        const unsigned short* gB0 = W2t + (size_t)(bn + (tid >> 2)) * DIN + (tid & 3) * 8;
        const unsigned short* gB1 = W2t + (size_t)(bn + 128 + (tid >> 2)) * DIN + (tid & 3) * 8;

        f32x4 acc[4][4];
#pragma unroll
        for (int m = 0; m < 4; ++m)
#pragma unroll
            for (int nn = 0; nn < 4; ++nn) acc[m][nn] = (f32x4){0.f, 0.f, 0.f, 0.f};

        const int aoff = (wr + (l & 15)) * 32 + (l >> 4) * 8;
        const int woff = 4096 + (wc + (l & 15)) * 32 + (l >> 4) * 8;
        const int ktiles = DIN >> 5;

        auto STAGE = [&](int buf, int kt) {
            unsigned short* lb = &S[buf * 12288];
            __builtin_amdgcn_global_load_lds(
                (const __attribute__((address_space(1))) void*)(gA + kt * 32),
                (__attribute__((address_space(3))) void*)(lb + se), 16, 0, 0);
            __builtin_amdgcn_global_load_lds(
                (const __attribute__((address_space(1))) void*)(gB0 + kt * 32),
                (__attribute__((address_space(3))) void*)(lb + 4096 + se), 16, 0, 0);
            __builtin_amdgcn_global_load_lds(
                (const __attribute__((address_space(1))) void*)(gB1 + kt * 32),
                (__attribute__((address_space(3))) void*)(lb + 8192 + se), 16, 0, 0);
        };

        STAGE(0, 0);
        __syncthreads();
        for (int kt = 0; kt < ktiles; ++kt) {
            if (kt + 1 < ktiles) STAGE((kt + 1) & 1, kt + 1);
            const int sb = (kt & 1) * 12288;
            bf16x8 af[4], wf[4];
#pragma unroll
            for (int m = 0; m < 4; ++m)
                af[m] = *(const bf16x8*)&S[sb + aoff + m * 512];
#pragma unroll
            for (int nn = 0; nn < 4; ++nn)
                wf[nn] = *(const bf16x8*)&S[sb + woff + nn * 512];
#pragma unroll
            for (int m = 0; m < 4; ++m)
#pragma unroll
                for (int nn = 0; nn < 4; ++nn)
                    acc[m][nn] = __builtin_amdgcn_mfma_f32_16x16x32_bf16(af[m], wf[nn], acc[m][nn], 0, 0, 0);
            __syncthreads();
        }

        const int r0 = bm + wr + (l >> 4) * 4;
        const int c0 = bn + wc + (l & 15);
#pragma unroll
        for (int nn = 0; nn < 4; ++nn) {
#pragma unroll
            for (int m = 0; m < 4; ++m) {
#pragma unroll
                for (int j = 0; j < 4; ++j) {
                    int gr = r0 + m * 16 + j;
                    if (gr < N_NODES)
                        P[(size_t)gr * HID + c0 + nn * 16] = f2b(acc[m][nn][j]);
                }
            }
        }
    } else {
        // ---- gather role: agg[node] = sum feat[src], 8 nodes/block ----
        const int EPL = DIN / 64;
        const int wid = tid >> 6;
        const int lane = tid & 63;
        const int node = (blockIdx.x - NP) * 8 + wid;
        if (node >= N_NODES) return;
        const int beg = off[node], end = off[node + 1];
        const int deg = end - beg;
        const int lb = lane * EPL;
        using VecT = typename std::conditional<EPL == 8, u16x8, u16x4>::type;

        float a0[EPL], a1[EPL], a2[EPL], a3[EPL];
#pragma unroll
        for (int j = 0; j < EPL; ++j) { a0[j] = 0.f; a1[j] = 0.f; a2[j] = 0.f; a3[j] = 0.f; }

        int idxv = 0;
#define ACC(ARR, SS)                                                        \
        {                                                                   \
            VecT v_ = *(const VecT*)(feat + (size_t)(SS) * DIN + lb);       \
            _Pragma("unroll")                                               \
            for (int j_ = 0; j_ < EPL; ++j_) ARR[j_] += b2f(v_[j_]);        \
        }
        for (int i = 0; i < deg; i += 4) {
            const int b = i & 63;
            if (b == 0) idxv = (beg + i + lane < end) ? esrc[beg + i + lane] : 0;
            const int s0 = __shfl(idxv, b);
            const int s1 = __shfl(idxv, b + 1);
            const int s2 = __shfl(idxv, b + 2);
            const int s3 = __shfl(idxv, b + 3);
            ACC(a0, s0);
            if (i + 1 < deg) ACC(a1, s1);
            if (i + 2 < deg) ACC(a2, s2);
            if (i + 3 < deg) ACC(a3, s3);
        }
#undef ACC
        unsigned short* op = agg + (size_t)node * DIN + lb;
        VecT h;
#pragma unroll
        for (int j = 0; j < EPL; ++j) h[j] = f2b(a0[j] + a1[j] + a2[j] + a3[j]);
        __builtin_nontemporal_store(h, (VecT*)op);
    }
}

// ---------------- GEMM2: out = agg @ W1t^T + P + bias ----------------
// Same verified 2-phase 128x256 structure; epilogue adds bf16 P and bias.
// FINAL=0: bf16 preact.  FINAL=1: f32 out.

template <int FINAL, int DIN>
__global__ __launch_bounds__(512, 2) void gemm2_kernel(
    const unsigned short* __restrict__ A, const unsigned short* __restrict__ B,
    const unsigned short* __restrict__ P, const float* __restrict__ bias,
    float* __restrict__ outF, unsigned short* __restrict__ pre) {
    __shared__ unsigned short S[2 * 12288];
    const int T = gridDim.x;          // 782
    const int q = T >> 3, r = T & 7;
    const int xcd = blockIdx.x & 7;
    const int n0 = blockIdx.x >> 3;
    const int g = xcd * q + min(xcd, r) + n0;
    const int bm = (g >> 1) * 128;
    const int bn = (g & 1) * 256;

    const int tid = threadIdx.x;
    const int l = tid & 63;
    const int w = tid >> 6;
    const int wr = (w >> 2) * 64;
    const int wc = (w & 3) * 64;

    const int se = (tid >> 2) * 32 + (tid & 3) * 8;
    const unsigned short* gA  = A + (size_t)(bm + (tid >> 2)) * DIN + (tid & 3) * 8;
    const unsigned short* gB0 = B + (size_t)(bn + (tid >> 2)) * DIN + (tid & 3) * 8;
    const unsigned short* gB1 = B + (size_t)(bn + 128 + (tid >> 2)) * DIN + (tid & 3) * 8;

    f32x4 acc[4][4];
#pragma unroll
    for (int m = 0; m < 4; ++m)
#pragma unroll
        for (int nn = 0; nn < 4; ++nn) acc[m][nn] = (f32x4){0.f, 0.f, 0.f, 0.f};

    const int aoff = (wr + (l & 15)) * 32 + (l >> 4) * 8;
    const int woff = 4096 + (wc + (l & 15)) * 32 + (l >> 4) * 8;
    const int ktiles = DIN >> 5;

    auto STAGE = [&](int buf, int kt) {
        unsigned short* lb = &S[buf * 12288];
        __builtin_amdgcn_global_load_lds(
            (const __attribute__((address_space(1))) void*)(gA + kt * 32),
            (__attribute__((address_space(3))) void*)(lb + se), 16, 0, 0);
        __builtin_amdgcn_global_load_lds(
            (const __attribute__((address_space(1))) void*)(gB0 + kt * 32),
            (__attribute__((address_space(3))) void*)(lb + 4096 + se), 16, 0, 0);
        __builtin_amdgcn_global_load_lds(
            (const __attribute__((address_space(1))) void*)(gB1 + kt * 32),
            (__attribute__((address_space(3))) void*)(lb + 8192 + se), 16, 0, 0);
    };

    STAGE(0, 0);
    __syncthreads();
    for (int kt = 0; kt < ktiles; ++kt) {
        if (kt + 1 < ktiles) STAGE((kt + 1) & 1, kt + 1);
        const int sb = (kt & 1) * 12288;
        bf16x8 af[4], wf[4];
#pragma unroll
        for (int m = 0; m < 4; ++m)
            af[m] = *(const bf16x8*)&S[sb + aoff + m * 512];
#pragma unroll
        for (int nn = 0; nn < 4; ++nn)
            wf[nn] = *(const bf16x8*)&S[sb + woff + nn * 512];
#pragma unroll
        for (int m = 0; m < 4; ++m)
#pragma unroll
            for (int nn = 0; nn < 4; ++nn)
                acc[m][nn] = __builtin_amdgcn_mfma_f32_16x16x32_bf16(af[m], wf[nn], acc[m][nn], 0, 0, 0);
        __syncthreads();
    }

    const int r0 = bm + wr + (l >> 4) * 4;
    const int c0 = bn + wc + (l & 15);
#pragma unroll
    for (int nn = 0; nn < 4; ++nn) {
        const float bv = bias[c0 + nn * 16];
#pragma unroll
        for (int m = 0; m < 4; ++m) {
#pragma unroll
            for (int j = 0; j < 4; ++j) {
                int gr = r0 + m * 16 + j;
                if (gr < N_NODES) {
                    float val = acc[m][nn][j] + bv
                              + b2f(P[(size_t)gr * HID + c0 + nn * 16]);
                    if constexpr (FINAL)
                        outF[(size_t)gr * HID + c0 + nn * 16] = val;
                    else
                        pre[(size_t)gr * HID + c0 + nn * 16] = f2b(val);
                }
            }
        }
    }
}

// ---------------- row L2-normalize + ELU (wave-per-row) ----------------
// FINAL=0: read bf16 preact [M][512], write bf16 feat [M][512].
// FINAL=1: read/write f32 outF in place.

template <int FINAL>
__global__ __launch_bounds__(256) void norm_elu_kernel(const void* __restrict__ inp,
                                                       float* __restrict__ outF,
                                                       unsigned short* __restrict__ feat) {
    const int wid = threadIdx.x >> 6;
    const int lane = threadIdx.x & 63;
    const int row = blockIdx.x * 4 + wid;
    if (row >= N_NODES) return;
    float r[8];
    if constexpr (FINAL) {
        const float* p = (const float*)inp + (size_t)row * HID + lane * 8;
        float4 v0 = *(const float4*)p;
        float4 v1 = *(const float4*)(p + 4);
        r[0] = v0.x; r[1] = v0.y; r[2] = v0.z; r[3] = v0.w;
        r[4] = v1.x; r[5] = v1.y; r[6] = v1.z; r[7] = v1.w;
    } else {
        const unsigned short* p = (const unsigned short*)inp + (size_t)row * HID + lane * 8;
        u16x8 v = *(const u16x8*)p;
#pragma unroll
        for (int j = 0; j < 8; ++j) r[j] = b2f(v[j]);
    }
    float ss = 0.f;
#pragma unroll
    for (int j = 0; j < 8; ++j) ss += r[j] * r[j];
#pragma unroll
    for (int o = 32; o > 0; o >>= 1) ss += __shfl_xor(ss, o);
    float inv = 1.f / fmaxf(sqrtf(ss), 1e-12f);
#pragma unroll
    for (int j = 0; j < 8; ++j) {
        r[j] *= inv;
        r[j] = r[j] > 0.f ? r[j] : expm1f(r[j]);
    }
    if constexpr (FINAL) {
        float* qp = outF + (size_t)row * HID + lane * 8;
        *(float4*)qp = make_float4(r[0], r[1], r[2], r[3]);
        *(float4*)(qp + 4) = make_float4(r[4], r[5], r[6], r[7]);
    } else {
        unsigned short* qp = feat + (size_t)row * HID + lane * 8;
        u16x8 h;
#pragma unroll
        for (int j = 0; j < 8; ++j) h[j] = f2b(r[j]);
        *(u16x8*)qp = h;
    }
}

// ---------------- launch ----------------

extern "C" void kernel_launch(void* const* d_in, const int* in_sizes, int n_in,
                              void* d_out, int out_size, void* d_ws, size_t ws_size,
                              hipStream_t stream) {
    const float* x    = (const float*)d_in[0];
    const void*  eidx = d_in[1];
    const float* Wl0 = (const float*)d_in[2];
    const float* bl0 = (const float*)d_in[3];
    const float* Wr0 = (const float*)d_in[4];
    const float* Wl1 = (const float*)d_in[5];
    const float* bl1 = (const float*)d_in[6];
    const float* Wr1 = (const float*)d_in[7];
    const float* Wl2 = (const float*)d_in[8];
    const float* bl2 = (const float*)d_in[9];
    const float* Wr2 = (const float*)d_in[10];
    float* outF = (float*)d_out;
    unsigned short* preB = (unsigned short*)d_out;  // bf16 preact scratch (layers 1-2)

    char* ws = (char*)d_ws;
    size_t o = 0;
    auto alloc = [&](size_t bytes) { void* p = ws + o; o += (bytes + 255) & ~(size_t)255; return p; };

    // separate planes (concat layout no longer needed)
    unsigned short* featB = (unsigned short*)alloc((size_t)M_PAD * 512 * 2);  // also featB1 [M][256]
    unsigned short* aggB  = (unsigned short*)alloc((size_t)M_PAD * 512 * 2);
    unsigned short* Pbuf  = (unsigned short*)alloc((size_t)M_PAD * 512 * 2);

    unsigned short* Wl0t = (unsigned short*)alloc(512 * 256 * 2);
    unsigned short* Wr0t = (unsigned short*)alloc(512 * 256 * 2);
    unsigned short* Wl1t = (unsigned short*)alloc(512 * 512 * 2);
    unsigned short* Wr1t = (unsigned short*)alloc(512 * 512 * 2);
    unsigned short* Wl2t = (unsigned short*)alloc(512 * 512 * 2);
    unsigned short* Wr2t = (unsigned short*)alloc(512 * 512 * 2);

    // counts/cursor MUST be one contiguous block (R2/R3 lesson).
    int* counts   = (int*)alloc((size_t)2 * N_NODES * 4);
    int* cursor   = counts + N_NODES;
    int* offsets  = (int*)alloc((size_t)(N_NODES + 1) * 4);
    int* edge_src = (int*)alloc((size_t)N_EDGES * 4);
    int* flag     = (int*)alloc(256);

    // ---- CSR build ----
    zero_detect_kernel<<<(2 * N_NODES + 255) / 256, 256, 0, stream>>>(
        counts, 2 * N_NODES, (const int*)eidx, flag);
    hist_kernel<<<(N_EDGES + 255) / 256, 256, 0, stream>>>(eidx, flag, counts);
    scan_kernel<<<1, 1024, 0, stream>>>(counts, offsets);
    fill_kernel<<<(N_EDGES + 255) / 256, 256, 0, stream>>>(eidx, flag, offsets, cursor, edge_src);

    // ---- conversions ----
    xconv_kernel<<<(M_PAD * 64 + 255) / 256, 256, 0, stream>>>(x, featB);
    {
        dim3 wgrid(512, 6);
        wconv_all_kernel<<<wgrid, 128, 0, stream>>>(Wl0, Wr0, Wl1, Wr1, Wl2, Wr2,
                                                    Wl0t, Wr0t, Wl1t, Wr1t, Wl2t, Wr2t);
    }

    const int NP = 2 * (M_PAD / 128);        // 782 GEMM-role blocks
    const int NG = (N_NODES + 7) / 8;        // 6250 gather-role blocks
    const int nchunk = (N_NODES + 3) / 4;

    // layer 1 (DIN=256): fat = [P = x@Wr0 | gather x] ; gemm2 = agg@Wl0 + P
    fat_kernel<256><<<NP + NG, 512, 0, stream>>>(featB, Wr0t, Pbuf, offsets, edge_src, aggB, NP);
    gemm2_kernel<0, 256><<<NP, 512, 0, stream>>>(aggB, Wl0t, Pbuf, bl0, nullptr, preB);
    norm_elu_kernel<0><<<nchunk, 256, 0, stream>>>(preB, nullptr, featB);

    // layer 2 (DIN=512)
    fat_kernel<512><<<NP + NG, 512, 0, stream>>>(featB, Wr1t, Pbuf, offsets, edge_src, aggB, NP);
    gemm2_kernel<0, 512><<<NP, 512, 0, stream>>>(aggB, Wl1t, Pbuf, bl1, nullptr, preB);
    norm_elu_kernel<0><<<nchunk, 256, 0, stream>>>(preB, nullptr, featB);

    // layer 3 (DIN=512): final -> f32
    fat_kernel<512><<<NP + NG, 512, 0, stream>>>(featB, Wr2t, Pbuf, offsets, edge_src, aggB, NP);
    gemm2_kernel<1, 512><<<NP, 512, 0, stream>>>(aggB, Wl2t, Pbuf, bl2, outF, nullptr);
    norm_elu_kernel<1><<<nchunk, 256, 0, stream>>>(outF, outF, nullptr);

    (void)in_sizes; (void)n_in; (void)out_size; (void)ws_size;
}

// Round 15
// 949.698 us; speedup vs baseline: 1.1409x; 1.1409x over previous
//
#include <hip/hip_runtime.h>
#include <math.h>

#define N_NODES 50000
#define M_PAD   50048   // 391 * 128
#define N_EDGES 800000
#define HID 512

typedef short bf16x8 __attribute__((ext_vector_type(8)));
typedef float f32x4  __attribute__((ext_vector_type(4)));
typedef unsigned short u16x4 __attribute__((ext_vector_type(4)));
typedef unsigned short u16x8 __attribute__((ext_vector_type(8)));

__device__ inline float b2f(unsigned short u) {
    union { unsigned int i; float f; } v; v.i = ((unsigned int)u) << 16; return v.f;
}
__device__ inline unsigned short f2b(float f) {
    union { float f; unsigned int i; } v; v.f = f;
    unsigned int r = v.i + 0x7FFFu + ((v.i >> 16) & 1u);
    return (unsigned short)(r >> 16);
}

// ---------------- CSR build ----------------

__global__ void zero_detect_kernel(int* __restrict__ p, int n,
                                   const int* __restrict__ e, int* __restrict__ flag) {
    int i = blockIdx.x * blockDim.x + threadIdx.x;
    if (i < n) p[i] = 0;
    if (blockIdx.x == 0 && threadIdx.x == 0) {
        int is64 = 1;
        for (int k = 0; k < 16; ++k)
            if (e[2 * k + 1] != 0) is64 = 0;
        *flag = is64;
    }
}

__global__ void hist_kernel(const void* __restrict__ eidx, const int* __restrict__ flag,
                            int* __restrict__ counts) {
    int e = blockIdx.x * blockDim.x + threadIdx.x;
    if (e >= N_EDGES) return;
    int is64 = *flag;
    int d;
    if (is64) d = (int)((const long long*)eidx)[N_EDGES + e];
    else      d = ((const int*)eidx)[N_EDGES + e];
    atomicAdd(&counts[d], 1);
}

__global__ __launch_bounds__(1024) void scan_kernel(const int* __restrict__ counts,
                                                    int* __restrict__ offsets) {
    __shared__ int sums[1024];
    int t = threadIdx.x;
    const int CH = (N_NODES + 1023) / 1024;  // 49
    int lo = t * CH;
    int hi = min(lo + CH, N_NODES);
    int s = 0;
    for (int i = lo; i < hi; ++i) s += counts[i];
    sums[t] = s;
    __syncthreads();
    for (int off = 1; off < 1024; off <<= 1) {
        int v = 0;
        if (t >= off) v = sums[t - off];
        __syncthreads();
        sums[t] += v;
        __syncthreads();
    }
    int excl = (t == 0) ? 0 : sums[t - 1];
    for (int i = lo; i < hi; ++i) { offsets[i] = excl; excl += counts[i]; }
    if (t == 1023) offsets[N_NODES] = excl;
}

__global__ void fill_kernel(const void* __restrict__ eidx, const int* __restrict__ flag,
                            const int* __restrict__ offsets, int* __restrict__ cursor,
                            int* __restrict__ edge_src) {
    int e = blockIdx.x * blockDim.x + threadIdx.x;
    if (e >= N_EDGES) return;
    int is64 = *flag;
    int s, d;
    if (is64) {
        const long long* p = (const long long*)eidx;
        s = (int)p[e];
        d = (int)p[N_EDGES + e];
    } else {
        const int* p = (const int*)eidx;
        s = p[e];
        d = p[N_EDGES + e];
    }
    int pos = atomicAdd(&cursor[d], 1);
    edge_src[offsets[d] + pos] = s;
}

// ---------------- conversions ----------------

__global__ __launch_bounds__(256) void xconv_kernel(const float* __restrict__ x,
                                                    unsigned short* __restrict__ feat) {
    int id = blockIdx.x * 256 + threadIdx.x;
    if (id >= M_PAD * 64) return;
    int row = id >> 6;
    int c = (id & 63) * 4;
    float4 v = make_float4(0.f, 0.f, 0.f, 0.f);
    if (row < N_NODES) v = *(const float4*)(x + (size_t)row * 256 + c);
    ushort4 h;
    h.x = f2b(v.x); h.y = f2b(v.y); h.z = f2b(v.z); h.w = f2b(v.w);
    *(ushort4*)(feat + (size_t)row * 256 + c) = h;
}

__global__ __launch_bounds__(128) void wconv_all_kernel(
    const float* __restrict__ Wl0, const float* __restrict__ Wr0,
    const float* __restrict__ Wl1, const float* __restrict__ Wr1,
    const float* __restrict__ Wl2, const float* __restrict__ Wr2,
    unsigned short* __restrict__ Tl0, unsigned short* __restrict__ Tr0,
    unsigned short* __restrict__ Tl1, unsigned short* __restrict__ Tr1,
    unsigned short* __restrict__ Tl2, unsigned short* __restrict__ Tr2) {
    const int y = blockIdx.y;
    const float* W = (y == 0) ? Wl0 : (y == 1) ? Wr0 : (y == 2) ? Wl1
                   : (y == 3) ? Wr1 : (y == 4) ? Wl2 : Wr2;
    unsigned short* T = (y == 0) ? Tl0 : (y == 1) ? Tr0 : (y == 2) ? Tl1
                      : (y == 3) ? Tr1 : (y == 4) ? Tl2 : Tr2;
    const int K = (y < 2) ? 256 : 512;
    int n = blockIdx.x;  // 0..511
    for (int k = threadIdx.x; k < K; k += 128)
        T[(size_t)n * K + k] = f2b(W[(size_t)k * HID + n]);
}

// ---------------- FAT kernel: gather blocks (first) + P-GEMM blocks ----------------
// 256 threads, 32 KB LDS -> 5 blocks/CU (fixes R14's occupancy collapse: 48KB/512t
// gave 2 blocks/CU and the gather starved at 2.4 TB/s).
// Blocks < NG: R13-verified 4-chain row-gather, 4 nodes/block: agg <- sum feat[src].
// Blocks >= NG: R7-verified 128x128 2-phase MFMA GEMM: P = feat @ W2t^T (bf16, no
//   bias), with bijective per-role XCD swizzle (4 bn-blocks of one A panel share
//   an XCD's L2).  Both roles read only `feat` -> P rides in the gather's shadow.

template <int DIN>
__global__ __launch_bounds__(256, 4) void fat_kernel(
    const unsigned short* __restrict__ feat, const unsigned short* __restrict__ W2t,
    unsigned short* __restrict__ P,
    const int* __restrict__ off, const int* __restrict__ esrc,
    unsigned short* __restrict__ agg, int NG, int NP) {
    __shared__ unsigned short S[2 * 8192];  // 2 buf x (A 4096 + B 4096) u16 = 32 KB
    const int tid = threadIdx.x;

    if ((int)blockIdx.x < NG) {
        // ---- gather role: agg[node] = sum feat[src], 4 nodes/block ----
        const int EPL = DIN / 64;
        const int wid = tid >> 6;
        const int lane = tid & 63;
        const int node = blockIdx.x * 4 + wid;
        if (node >= N_NODES) return;
        const int beg = off[node], end = off[node + 1];
        const int deg = end - beg;
        const int lb = lane * EPL;
        using VecT = typename std::conditional<EPL == 8, u16x8, u16x4>::type;

        float a0[EPL], a1[EPL], a2[EPL], a3[EPL];
#pragma unroll
        for (int j = 0; j < EPL; ++j) { a0[j] = 0.f; a1[j] = 0.f; a2[j] = 0.f; a3[j] = 0.f; }

        int idxv = 0;
#define ACC(ARR, SS)                                                        \
        {                                                                   \
            VecT v_ = *(const VecT*)(feat + (size_t)(SS) * DIN + lb);       \
            _Pragma("unroll")                                               \
            for (int j_ = 0; j_ < EPL; ++j_) ARR[j_] += b2f(v_[j_]);        \
        }
        for (int i = 0; i < deg; i += 4) {
            const int b = i & 63;
            if (b == 0) idxv = (beg + i + lane < end) ? esrc[beg + i + lane] : 0;
            const int s0 = __shfl(idxv, b);
            const int s1 = __shfl(idxv, b + 1);
            const int s2 = __shfl(idxv, b + 2);
            const int s3 = __shfl(idxv, b + 3);
            ACC(a0, s0);
            if (i + 1 < deg) ACC(a1, s1);
            if (i + 2 < deg) ACC(a2, s2);
            if (i + 3 < deg) ACC(a3, s3);
        }
#undef ACC
        unsigned short* op = agg + (size_t)node * DIN + lb;
        VecT h;
#pragma unroll
        for (int j = 0; j < EPL; ++j) h[j] = f2b(a0[j] + a1[j] + a2[j] + a3[j]);
        __builtin_nontemporal_store(h, (VecT*)op);
    } else {
        // ---- P-GEMM role: P[M][512] = feat[M][DIN] @ W2t[512][DIN]^T ----
        const int i = blockIdx.x - NG;
        const int q = NP >> 3, r = NP & 7;
        const int xcd = i & 7;
        const int n0 = i >> 3;
        const int g = xcd * q + min(xcd, r) + n0;  // bijective (ERRATA #11)
        const int bm = (g >> 2) * 128;
        const int bn = (g & 3) * 128;

        const int l = tid & 63;
        const int w = tid >> 6;
        const int wr = (w >> 1) * 64;
        const int wc = (w & 1) * 64;
        const int arow = l >> 2;
        const int acol = (l & 3) * 8;

        const unsigned short* gA = feat + (size_t)(bm + arow) * DIN + acol;
        const unsigned short* gB = W2t + (size_t)(bn + arow) * DIN + acol;

        f32x4 acc[4][4];
#pragma unroll
        for (int m = 0; m < 4; ++m)
#pragma unroll
            for (int nn = 0; nn < 4; ++nn) acc[m][nn] = (f32x4){0.f, 0.f, 0.f, 0.f};

        const int aoff = (wr + (l & 15)) * 32 + (l >> 4) * 8;
        const int woff = 4096 + (wc + (l & 15)) * 32 + (l >> 4) * 8;
        const int ktiles = DIN >> 5;

        auto STAGE = [&](int buf, int kt) {
            unsigned short* lb = &S[buf * 8192];
#pragma unroll
            for (int i2 = 0; i2 < 2; ++i2) {
                const int c = w * 2 + i2;  // 16-row chunk, 0..7
                __builtin_amdgcn_global_load_lds(
                    (const __attribute__((address_space(1))) void*)(gA + (size_t)(c * 16) * DIN + kt * 32),
                    (__attribute__((address_space(3))) void*)(lb + c * 512), 16, 0, 0);
                __builtin_amdgcn_global_load_lds(
                    (const __attribute__((address_space(1))) void*)(gB + (size_t)(c * 16) * DIN + kt * 32),
                    (__attribute__((address_space(3))) void*)(lb + 4096 + c * 512), 16, 0, 0);
            }
        };

        STAGE(0, 0);
        __syncthreads();
        for (int kt = 0; kt < ktiles; ++kt) {
            if (kt + 1 < ktiles) STAGE((kt + 1) & 1, kt + 1);
            const int sb = (kt & 1) * 8192;
            bf16x8 af[4], wf[4];
#pragma unroll
            for (int m = 0; m < 4; ++m)
                af[m] = *(const bf16x8*)&S[sb + aoff + m * 512];
#pragma unroll
            for (int nn = 0; nn < 4; ++nn)
                wf[nn] = *(const bf16x8*)&S[sb + woff + nn * 512];
#pragma unroll
            for (int m = 0; m < 4; ++m)
#pragma unroll
                for (int nn = 0; nn < 4; ++nn)
                    acc[m][nn] = __builtin_amdgcn_mfma_f32_16x16x32_bf16(af[m], wf[nn], acc[m][nn], 0, 0, 0);
            __syncthreads();
        }

        const int r0 = bm + wr + (l >> 4) * 4;
        const int c0 = bn + wc + (l & 15);
#pragma unroll
        for (int nn = 0; nn < 4; ++nn) {
#pragma unroll
            for (int m = 0; m < 4; ++m) {
#pragma unroll
                for (int j = 0; j < 4; ++j) {
                    int gr = r0 + m * 16 + j;
                    if (gr < N_NODES)
                        P[(size_t)gr * HID + c0 + nn * 16] = f2b(acc[m][nn][j]);
                }
            }
        }
    }
}

// ---------------- GEMM2: out = agg @ W1t^T + P + bias ----------------
// R13/R14-verified 2-phase 128x256 8-wave structure; epilogue adds bf16 P + bias.

template <int FINAL, int DIN>
__global__ __launch_bounds__(512, 2) void gemm2_kernel(
    const unsigned short* __restrict__ A, const unsigned short* __restrict__ B,
    const unsigned short* __restrict__ P, const float* __restrict__ bias,
    float* __restrict__ outF, unsigned short* __restrict__ pre) {
    __shared__ unsigned short S[2 * 12288];
    const int T = gridDim.x;          // 782
    const int q = T >> 3, r = T & 7;
    const int xcd = blockIdx.x & 7;
    const int n0 = blockIdx.x >> 3;
    const int g = xcd * q + min(xcd, r) + n0;
    const int bm = (g >> 1) * 128;
    const int bn = (g & 1) * 256;

    const int tid = threadIdx.x;
    const int l = tid & 63;
    const int w = tid >> 6;
    const int wr = (w >> 2) * 64;
    const int wc = (w & 3) * 64;

    const int se = (tid >> 2) * 32 + (tid & 3) * 8;
    const unsigned short* gA  = A + (size_t)(bm + (tid >> 2)) * DIN + (tid & 3) * 8;
    const unsigned short* gB0 = B + (size_t)(bn + (tid >> 2)) * DIN + (tid & 3) * 8;
    const unsigned short* gB1 = B + (size_t)(bn + 128 + (tid >> 2)) * DIN + (tid & 3) * 8;

    f32x4 acc[4][4];
#pragma unroll
    for (int m = 0; m < 4; ++m)
#pragma unroll
        for (int nn = 0; nn < 4; ++nn) acc[m][nn] = (f32x4){0.f, 0.f, 0.f, 0.f};

    const int aoff = (wr + (l & 15)) * 32 + (l >> 4) * 8;
    const int woff = 4096 + (wc + (l & 15)) * 32 + (l >> 4) * 8;
    const int ktiles = DIN >> 5;

    auto STAGE = [&](int buf, int kt) {
        unsigned short* lb = &S[buf * 12288];
        __builtin_amdgcn_global_load_lds(
            (const __attribute__((address_space(1))) void*)(gA + kt * 32),
            (__attribute__((address_space(3))) void*)(lb + se), 16, 0, 0);
        __builtin_amdgcn_global_load_lds(
            (const __attribute__((address_space(1))) void*)(gB0 + kt * 32),
            (__attribute__((address_space(3))) void*)(lb + 4096 + se), 16, 0, 0);
        __builtin_amdgcn_global_load_lds(
            (const __attribute__((address_space(1))) void*)(gB1 + kt * 32),
            (__attribute__((address_space(3))) void*)(lb + 8192 + se), 16, 0, 0);
    };

    STAGE(0, 0);
    __syncthreads();
    for (int kt = 0; kt < ktiles; ++kt) {
        if (kt + 1 < ktiles) STAGE((kt + 1) & 1, kt + 1);
        const int sb = (kt & 1) * 12288;
        bf16x8 af[4], wf[4];
#pragma unroll
        for (int m = 0; m < 4; ++m)
            af[m] = *(const bf16x8*)&S[sb + aoff + m * 512];
#pragma unroll
        for (int nn = 0; nn < 4; ++nn)
            wf[nn] = *(const bf16x8*)&S[sb + woff + nn * 512];
#pragma unroll
        for (int m = 0; m < 4; ++m)
#pragma unroll
            for (int nn = 0; nn < 4; ++nn)
                acc[m][nn] = __builtin_amdgcn_mfma_f32_16x16x32_bf16(af[m], wf[nn], acc[m][nn], 0, 0, 0);
        __syncthreads();
    }

    const int r0 = bm + wr + (l >> 4) * 4;
    const int c0 = bn + wc + (l & 15);
#pragma unroll
    for (int nn = 0; nn < 4; ++nn) {
        const float bv = bias[c0 + nn * 16];
#pragma unroll
        for (int m = 0; m < 4; ++m) {
#pragma unroll
            for (int j = 0; j < 4; ++j) {
                int gr = r0 + m * 16 + j;
                if (gr < N_NODES) {
                    float val = acc[m][nn][j] + bv
                              + b2f(P[(size_t)gr * HID + c0 + nn * 16]);
                    if constexpr (FINAL)
                        outF[(size_t)gr * HID + c0 + nn * 16] = val;
                    else
                        pre[(size_t)gr * HID + c0 + nn * 16] = f2b(val);
                }
            }
        }
    }
}

// ---------------- row L2-normalize + ELU (wave-per-row) ----------------

template <int FINAL>
__global__ __launch_bounds__(256) void norm_elu_kernel(const void* __restrict__ inp,
                                                       float* __restrict__ outF,
                                                       unsigned short* __restrict__ feat) {
    const int wid = threadIdx.x >> 6;
    const int lane = threadIdx.x & 63;
    const int row = blockIdx.x * 4 + wid;
    if (row >= N_NODES) return;
    float r[8];
    if constexpr (FINAL) {
        const float* p = (const float*)inp + (size_t)row * HID + lane * 8;
        float4 v0 = *(const float4*)p;
        float4 v1 = *(const float4*)(p + 4);
        r[0] = v0.x; r[1] = v0.y; r[2] = v0.z; r[3] = v0.w;
        r[4] = v1.x; r[5] = v1.y; r[6] = v1.z; r[7] = v1.w;
    } else {
        const unsigned short* p = (const unsigned short*)inp + (size_t)row * HID + lane * 8;
        u16x8 v = *(const u16x8*)p;
#pragma unroll
        for (int j = 0; j < 8; ++j) r[j] = b2f(v[j]);
    }
    float ss = 0.f;
#pragma unroll
    for (int j = 0; j < 8; ++j) ss += r[j] * r[j];
#pragma unroll
    for (int o = 32; o > 0; o >>= 1) ss += __shfl_xor(ss, o);
    float inv = 1.f / fmaxf(sqrtf(ss), 1e-12f);
#pragma unroll
    for (int j = 0; j < 8; ++j) {
        r[j] *= inv;
        r[j] = r[j] > 0.f ? r[j] : expm1f(r[j]);
    }
    if constexpr (FINAL) {
        float* qp = outF + (size_t)row * HID + lane * 8;
        *(float4*)qp = make_float4(r[0], r[1], r[2], r[3]);
        *(float4*)(qp + 4) = make_float4(r[4], r[5], r[6], r[7]);
    } else {
        unsigned short* qp = feat + (size_t)row * HID + lane * 8;
        u16x8 h;
#pragma unroll
        for (int j = 0; j < 8; ++j) h[j] = f2b(r[j]);
        *(u16x8*)qp = h;
    }
}

// ---------------- launch ----------------

extern "C" void kernel_launch(void* const* d_in, const int* in_sizes, int n_in,
                              void* d_out, int out_size, void* d_ws, size_t ws_size,
                              hipStream_t stream) {
    const float* x    = (const float*)d_in[0];
    const void*  eidx = d_in[1];
    const float* Wl0 = (const float*)d_in[2];
    const float* bl0 = (const float*)d_in[3];
    const float* Wr0 = (const float*)d_in[4];
    const float* Wl1 = (const float*)d_in[5];
    const float* bl1 = (const float*)d_in[6];
    const float* Wr1 = (const float*)d_in[7];
    const float* Wl2 = (const float*)d_in[8];
    const float* bl2 = (const float*)d_in[9];
    const float* Wr2 = (const float*)d_in[10];
    float* outF = (float*)d_out;
    unsigned short* preB = (unsigned short*)d_out;  // bf16 preact scratch (layers 1-2)

    char* ws = (char*)d_ws;
    size_t o = 0;
    auto alloc = [&](size_t bytes) { void* p = ws + o; o += (bytes + 255) & ~(size_t)255; return p; };

    unsigned short* featB = (unsigned short*)alloc((size_t)M_PAD * 512 * 2);  // [M][256] for layer 1
    unsigned short* aggB  = (unsigned short*)alloc((size_t)M_PAD * 512 * 2);
    unsigned short* Pbuf  = (unsigned short*)alloc((size_t)M_PAD * 512 * 2);

    unsigned short* Wl0t = (unsigned short*)alloc(512 * 256 * 2);
    unsigned short* Wr0t = (unsigned short*)alloc(512 * 256 * 2);
    unsigned short* Wl1t = (unsigned short*)alloc(512 * 512 * 2);
    unsigned short* Wr1t = (unsigned short*)alloc(512 * 512 * 2);
    unsigned short* Wl2t = (unsigned short*)alloc(512 * 512 * 2);
    unsigned short* Wr2t = (unsigned short*)alloc(512 * 512 * 2);

    // counts/cursor MUST be one contiguous block (R2/R3 lesson).
    int* counts   = (int*)alloc((size_t)2 * N_NODES * 4);
    int* cursor   = counts + N_NODES;
    int* offsets  = (int*)alloc((size_t)(N_NODES + 1) * 4);
    int* edge_src = (int*)alloc((size_t)N_EDGES * 4);
    int* flag     = (int*)alloc(256);

    // ---- CSR build ----
    zero_detect_kernel<<<(2 * N_NODES + 255) / 256, 256, 0, stream>>>(
        counts, 2 * N_NODES, (const int*)eidx, flag);
    hist_kernel<<<(N_EDGES + 255) / 256, 256, 0, stream>>>(eidx, flag, counts);
    scan_kernel<<<1, 1024, 0, stream>>>(counts, offsets);
    fill_kernel<<<(N_EDGES + 255) / 256, 256, 0, stream>>>(eidx, flag, offsets, cursor, edge_src);

    // ---- conversions ----
    xconv_kernel<<<(M_PAD * 64 + 255) / 256, 256, 0, stream>>>(x, featB);
    {
        dim3 wgrid(512, 6);
        wconv_all_kernel<<<wgrid, 128, 0, stream>>>(Wl0, Wr0, Wl1, Wr1, Wl2, Wr2,
                                                    Wl0t, Wr0t, Wl1t, Wr1t, Wl2t, Wr2t);
    }

    const int NG  = (N_NODES + 3) / 4;       // 12500 gather-role blocks (first)
    const int NP  = 4 * (M_PAD / 128);       // 1564 P-GEMM-role blocks (128x128 tile)
    const int NP2 = 2 * (M_PAD / 128);       // 782 gemm2 blocks (128x256 tile)
    const int nchunk = (N_NODES + 3) / 4;

    // layer 1 (DIN=256): fat = [gather x | P = x@Wr0] ; gemm2 = agg@Wl0 + P
    fat_kernel<256><<<NG + NP, 256, 0, stream>>>(featB, Wr0t, Pbuf, offsets, edge_src, aggB, NG, NP);
    gemm2_kernel<0, 256><<<NP2, 512, 0, stream>>>(aggB, Wl0t, Pbuf, bl0, nullptr, preB);
    norm_elu_kernel<0><<<nchunk, 256, 0, stream>>>(preB, nullptr, featB);

    // layer 2 (DIN=512)
    fat_kernel<512><<<NG + NP, 256, 0, stream>>>(featB, Wr1t, Pbuf, offsets, edge_src, aggB, NG, NP);
    gemm2_kernel<0, 512><<<NP2, 512, 0, stream>>>(aggB, Wl1t, Pbuf, bl1, nullptr, preB);
    norm_elu_kernel<0><<<nchunk, 256, 0, stream>>>(preB, nullptr, featB);

    // layer 3 (DIN=512): final -> f32
    fat_kernel<512><<<NG + NP, 256, 0, stream>>>(featB, Wr2t, Pbuf, offsets, edge_src, aggB, NG, NP);
    gemm2_kernel<1, 512><<<NP2, 512, 0, stream>>>(aggB, Wl2t, Pbuf, bl2, outF, nullptr);
    norm_elu_kernel<1><<<nchunk, 256, 0, stream>>>(outF, outF, nullptr);

    (void)in_sizes; (void)n_in; (void)out_size; (void)ws_size;
}

// Round 17
// 801.860 us; speedup vs baseline: 1.3513x; 1.1844x over previous
//
#include <hip/hip_runtime.h>
#include <math.h>

#define N_NODES 50000
#define M_PAD   50176   // 196 * 256 (8-phase GEMM uses 256-row tiles)
#define N_EDGES 800000
#define HID 512

typedef short bf16x8 __attribute__((ext_vector_type(8)));
typedef float f32x4  __attribute__((ext_vector_type(4)));
typedef unsigned short u16x4 __attribute__((ext_vector_type(4)));
typedef unsigned short u16x8 __attribute__((ext_vector_type(8)));

__device__ inline float b2f(unsigned short u) {
    union { unsigned int i; float f; } v; v.i = ((unsigned int)u) << 16; return v.f;
}
__device__ inline unsigned short f2b(float f) {
    union { float f; unsigned int i; } v; v.f = f;
    unsigned int r = v.i + 0x7FFFu + ((v.i >> 16) & 1u);
    return (unsigned short)(r >> 16);
}

// ---------------- CSR build ----------------

__global__ void zero_detect_kernel(int* __restrict__ p, int n,
                                   const int* __restrict__ e, int* __restrict__ flag) {
    int i = blockIdx.x * blockDim.x + threadIdx.x;
    if (i < n) p[i] = 0;
    if (blockIdx.x == 0 && threadIdx.x == 0) {
        int is64 = 1;
        for (int k = 0; k < 16; ++k)
            if (e[2 * k + 1] != 0) is64 = 0;
        *flag = is64;
    }
}

__global__ void hist_kernel(const void* __restrict__ eidx, const int* __restrict__ flag,
                            int* __restrict__ counts) {
    int e = blockIdx.x * blockDim.x + threadIdx.x;
    if (e >= N_EDGES) return;
    int is64 = *flag;
    int d;
    if (is64) d = (int)((const long long*)eidx)[N_EDGES + e];
    else      d = ((const int*)eidx)[N_EDGES + e];
    atomicAdd(&counts[d], 1);
}

__global__ __launch_bounds__(1024) void scan_kernel(const int* __restrict__ counts,
                                                    int* __restrict__ offsets) {
    __shared__ int sums[1024];
    int t = threadIdx.x;
    const int CH = (N_NODES + 1023) / 1024;  // 49
    int lo = t * CH;
    int hi = min(lo + CH, N_NODES);
    int s = 0;
    for (int i = lo; i < hi; ++i) s += counts[i];
    sums[t] = s;
    __syncthreads();
    for (int off = 1; off < 1024; off <<= 1) {
        int v = 0;
        if (t >= off) v = sums[t - off];
        __syncthreads();
        sums[t] += v;
        __syncthreads();
    }
    int excl = (t == 0) ? 0 : sums[t - 1];
    for (int i = lo; i < hi; ++i) { offsets[i] = excl; excl += counts[i]; }
    if (t == 1023) offsets[N_NODES] = excl;
}

__global__ void fill_kernel(const void* __restrict__ eidx, const int* __restrict__ flag,
                            const int* __restrict__ offsets, int* __restrict__ cursor,
                            int* __restrict__ edge_src) {
    int e = blockIdx.x * blockDim.x + threadIdx.x;
    if (e >= N_EDGES) return;
    int is64 = *flag;
    int s, d;
    if (is64) {
        const long long* p = (const long long*)eidx;
        s = (int)p[e];
        d = (int)p[N_EDGES + e];
    } else {
        const int* p = (const int*)eidx;
        s = p[e];
        d = p[N_EDGES + e];
    }
    int pos = atomicAdd(&cursor[d], 1);
    edge_src[offsets[d] + pos] = s;
}

// ---------------- conversions ----------------

// x (f32 [N,256]) -> bf16 into feat-half of Cat1 ([M][512], cols 256..512)
__global__ __launch_bounds__(256) void xconv_kernel(const float* __restrict__ x,
                                                    unsigned short* __restrict__ cat1) {
    int id = blockIdx.x * 256 + threadIdx.x;
    if (id >= M_PAD * 64) return;
    int row = id >> 6;
    int c = (id & 63) * 4;
    float4 v = make_float4(0.f, 0.f, 0.f, 0.f);
    if (row < N_NODES) v = *(const float4*)(x + (size_t)row * 256 + c);
    ushort4 h;
    h.x = f2b(v.x); h.y = f2b(v.y); h.z = f2b(v.z); h.w = f2b(v.w);
    *(ushort4*)(cat1 + (size_t)row * 512 + 256 + c) = h;
}

// W (f32 [K,512]) -> transposed bf16 into Wcat[n][off + k], row stride ktot
__global__ __launch_bounds__(128) void wconv_kernel(const float* __restrict__ W,
                                                    unsigned short* __restrict__ T,
                                                    int K, int ktot, int off) {
    int n = blockIdx.x;  // 0..511
    for (int k = threadIdx.x; k < K; k += 128)
        T[(size_t)n * ktot + off + k] = f2b(W[(size_t)k * HID + n]);
}

// ---------------- aggregate: wave-per-node row-gather, 4 chains (R13-verified) ----------------

template <int EPL>
__global__ __launch_bounds__(256) void aggregate_kernel(const unsigned short* __restrict__ Fh,
                                                        const int* __restrict__ off,
                                                        const int* __restrict__ esrc,
                                                        unsigned short* __restrict__ Ah) {
    const int STRIDE = 2 * EPL * 64;
    const int wid = threadIdx.x >> 6;
    const int lane = threadIdx.x & 63;
    const int node = blockIdx.x * 4 + wid;
    if (node >= N_NODES) return;
    const int beg = off[node], end = off[node + 1];
    const int deg = end - beg;
    const int lb = lane * EPL;
    using VecT = typename std::conditional<EPL == 8, u16x8, u16x4>::type;

    float a0[EPL], a1[EPL], a2[EPL], a3[EPL];
#pragma unroll
    for (int j = 0; j < EPL; ++j) { a0[j] = 0.f; a1[j] = 0.f; a2[j] = 0.f; a3[j] = 0.f; }

    int idxv = 0;
#define ACC(ARR, S)                                                         \
    {                                                                       \
        VecT v_ = *(const VecT*)(Fh + (size_t)(S) * STRIDE + lb);           \
        _Pragma("unroll")                                                   \
        for (int j_ = 0; j_ < EPL; ++j_) ARR[j_] += b2f(v_[j_]);            \
    }
    for (int i = 0; i < deg; i += 4) {
        const int b = i & 63;
        if (b == 0) idxv = (beg + i + lane < end) ? esrc[beg + i + lane] : 0;
        const int s0 = __shfl(idxv, b);
        const int s1 = __shfl(idxv, b + 1);
        const int s2 = __shfl(idxv, b + 2);
        const int s3 = __shfl(idxv, b + 3);
        ACC(a0, s0);
        if (i + 1 < deg) ACC(a1, s1);
        if (i + 2 < deg) ACC(a2, s2);
        if (i + 3 < deg) ACC(a3, s3);
    }
#undef ACC
    unsigned short* op = Ah + (size_t)node * STRIDE + lb;
    VecT h;
#pragma unroll
    for (int j = 0; j < EPL; ++j) h[j] = f2b(a0[j] + a1[j] + a2[j] + a3[j]);
    __builtin_nontemporal_store(h, (VecT*)op);
}

// ---------------- 8-phase 256x256 MFMA GEMM (T3+T4+T2+T5) ----------------
// R16 bug fixed: reads of tile t are now only in phases AFTER the vmcnt+barrier
// covering t's loads.  Phases 0-3 read t0 (quadrants (K0,f0)(K0,f1)(K1,f0)(K1,f1));
// vmcnt(4) at ph3 -> tile t1 fully landed (ledger: issued 20+16i, completed 16+16i);
// phases 4-7 read t1; vmcnt(4) at ph7 covers t2.  Epilogue: skipped stages would
// make ph3's 4 allowed-outstanding be exactly the loads ph4/ph6 need -> re-stage
// (STT-2) instead (same parity => same buffer+region, identical bytes, benign).
// T2 swizzle: LDS[row][c] = G[row][c ^ ((row>>1)&3)] via pre-swizzled source col;
// read at c = ch ^ ((li>>1)&3).  T5 setprio around each 16-MFMA cluster.

template <int FINAL>
__global__ __launch_bounds__(512, 1) void gemm8_kernel(
    const unsigned short* __restrict__ A, const unsigned short* __restrict__ B,
    const float* __restrict__ bias, float* __restrict__ outF,
    unsigned short* __restrict__ pre, int K) {
    __shared__ unsigned short S[65536];  // 128 KB
    const int tid = threadIdx.x;
    const int l = tid & 63;
    const int w = tid >> 6;
    const int wm = w >> 2;     // 0..1
    const int wn = w & 3;      // 0..3
    const int li = l & 15;
    const int ch = l >> 4;

    // bijective XCD swizzle: grid 392 = 8*49; adjacent g share the A panel.
    const int g = (blockIdx.x & 7) * 49 + (blockIdx.x >> 3);
    const int bm = (g >> 1) * 256;
    const int bn = (g & 1) * 256;

    const int cswz = (ch ^ ((li >> 1) & 3)) * 8;             // swizzled read chunk
    const int srow = tid >> 2;                               // staging row
    const int scol = (((tid & 3) ^ ((tid >> 3) & 3)) * 8);   // pre-swizzled source col

    const int ktiles = K >> 6;   // BK=64
    const int nit = ktiles >> 1;

    // region r: 0=A-K0, 1=B-K0, 2=A-K1, 3=B-K1 (each 8192 elems = 256x32)
    auto STAGE = [&](int t, int r) {
        const bool isA = (r & 1) == 0;
        const int kh = r >> 1;
        const unsigned short* gsrc = isA ? (A + (size_t)(bm + srow) * K)
                                         : (B + (size_t)(bn + srow) * K);
        const unsigned short* g0 = gsrc + t * 64 + kh * 32 + scol;
        const unsigned short* g1 = g0 + (size_t)128 * K;
        unsigned short* lds = S + (t & 1) * 32768 + (isA ? 0 : 16384) + kh * 8192 + tid * 8;
        __builtin_amdgcn_global_load_lds(
            (const __attribute__((address_space(1))) void*)g0,
            (__attribute__((address_space(3))) void*)lds, 16, 0, 0);
        __builtin_amdgcn_global_load_lds(
            (const __attribute__((address_space(1))) void*)g1,
            (__attribute__((address_space(3))) void*)(lds + 4096), 16, 0, 0);
    };

    f32x4 acc[8][4];
#pragma unroll
    for (int m = 0; m < 8; ++m)
#pragma unroll
        for (int n = 0; n < 4; ++n) acc[m][n] = (f32x4){0.f, 0.f, 0.f, 0.f};

    bf16x8 bfrag[4];  // B frags persist across the (frh=0 -> frh=1) phase pair

    // prologue: t0 fully + t1 K0-halves; vmcnt(4) -> t0's 8 loads landed; barrier.
    STAGE(0, 0); STAGE(0, 1); STAGE(0, 2); STAGE(0, 3);
    STAGE(1, 0); STAGE(1, 1);
    asm volatile("s_waitcnt vmcnt(4)" ::: "memory");
    __builtin_amdgcn_s_barrier();

#define PHASE(VM, TCUR, KK, FRH, STT, STR)                                      \
    {                                                                           \
        const int sb = ((TCUR) & 1) * 32768;                                    \
        bf16x8 af[4];                                                           \
        _Pragma("unroll")                                                       \
        for (int fr = 0; fr < 4; ++fr)                                          \
            af[fr] = *(const bf16x8*)&S[sb + (KK)*8192 +                        \
                (wm * 128 + ((FRH)*4 + fr) * 16 + li) * 32 + cswz];             \
        if ((FRH) == 0) {                                                       \
            _Pragma("unroll")                                                   \
            for (int fc = 0; fc < 4; ++fc)                                      \
                bfrag[fc] = *(const bf16x8*)&S[sb + 16384 + (KK)*8192 +         \
                    (wn * 64 + fc * 16 + li) * 32 + cswz];                      \
        }                                                                       \
        STAGE(((STT) < ktiles) ? (STT) : (STT) - 2, (STR));                     \
        if (VM) asm volatile("s_waitcnt vmcnt(4)" ::: "memory");                \
        __builtin_amdgcn_s_barrier();                                           \
        __builtin_amdgcn_s_setprio(1);                                          \
        _Pragma("unroll")                                                       \
        for (int fr = 0; fr < 4; ++fr)                                          \
            _Pragma("unroll")                                                   \
            for (int fc = 0; fc < 4; ++fc)                                      \
                acc[(FRH)*4 + fr][fc] = __builtin_amdgcn_mfma_f32_16x16x32_bf16(\
                    af[fr], bfrag[fc], acc[(FRH)*4 + fr][fc], 0, 0, 0);         \
        __builtin_amdgcn_s_setprio(0);                                          \
        __builtin_amdgcn_s_barrier();                                           \
    }

    for (int i = 0; i < nit; ++i) {
        const int t0 = 2 * i;
        PHASE(0, t0,     0, 0, t0 + 1, 2);   // stage t1.A-K1
        PHASE(0, t0,     0, 1, t0 + 1, 3);   // stage t1.B-K1
        PHASE(0, t0,     1, 0, t0 + 2, 0);   // stage t2.A-K0 (t0.A-K0 retired ph1)
        PHASE(1, t0,     1, 1, t0 + 2, 1);   // stage t2.B-K0; vmcnt(4) -> t1 landed
        PHASE(0, t0 + 1, 0, 0, t0 + 2, 2);   // stage t2.A-K1
        PHASE(0, t0 + 1, 0, 1, t0 + 2, 3);   // stage t2.B-K1
        PHASE(0, t0 + 1, 1, 0, t0 + 3, 0);   // stage t3.A-K0
        PHASE(1, t0 + 1, 1, 1, t0 + 3, 1);   // stage t3.B-K0; vmcnt(4) -> t2 landed
    }
#undef PHASE

    const int r0 = bm + wm * 128 + ch * 4;
    const int c0 = bn + wn * 64 + li;
#pragma unroll
    for (int fc = 0; fc < 4; ++fc) {
        const float bv = bias[c0 + fc * 16];
#pragma unroll
        for (int fr = 0; fr < 8; ++fr) {
#pragma unroll
            for (int j = 0; j < 4; ++j) {
                int gr = r0 + fr * 16 + j;
                if (gr < N_NODES) {
                    float val = acc[fr][fc][j] + bv;
                    if constexpr (FINAL)
                        outF[(size_t)gr * HID + c0 + fc * 16] = val;
                    else
                        pre[(size_t)gr * HID + c0 + fc * 16] = f2b(val);
                }
            }
        }
    }
}

// ---------------- row L2-normalize + ELU (wave-per-row) ----------------

template <int FINAL>
__global__ __launch_bounds__(256) void norm_elu_kernel(const void* __restrict__ inp,
                                                       float* __restrict__ outF,
                                                       unsigned short* __restrict__ Fh) {
    const int wid = threadIdx.x >> 6;
    const int lane = threadIdx.x & 63;
    const int row = blockIdx.x * 4 + wid;
    if (row >= N_NODES) return;
    float r[8];
    if constexpr (FINAL) {
        const float* p = (const float*)inp + (size_t)row * HID + lane * 8;
        float4 v0 = *(const float4*)p;
        float4 v1 = *(const float4*)(p + 4);
        r[0] = v0.x; r[1] = v0.y; r[2] = v0.z; r[3] = v0.w;
        r[4] = v1.x; r[5] = v1.y; r[6] = v1.z; r[7] = v1.w;
    } else {
        const unsigned short* p = (const unsigned short*)inp + (size_t)row * HID + lane * 8;
        u16x8 v = *(const u16x8*)p;
#pragma unroll
        for (int j = 0; j < 8; ++j) r[j] = b2f(v[j]);
    }
    float ss = 0.f;
#pragma unroll
    for (int j = 0; j < 8; ++j) ss += r[j] * r[j];
#pragma unroll
    for (int o = 32; o > 0; o >>= 1) ss += __shfl_xor(ss, o);
    float inv = 1.f / fmaxf(sqrtf(ss), 1e-12f);
#pragma unroll
    for (int j = 0; j < 8; ++j) {
        r[j] *= inv;
        r[j] = r[j] > 0.f ? r[j] : expm1f(r[j]);
    }
    if constexpr (FINAL) {
        float* q = outF + (size_t)row * HID + lane * 8;
        *(float4*)q = make_float4(r[0], r[1], r[2], r[3]);
        *(float4*)(q + 4) = make_float4(r[4], r[5], r[6], r[7]);
    } else {
        unsigned short* q = Fh + (size_t)row * 1024 + lane * 8;
        u16x8 h;
#pragma unroll
        for (int j = 0; j < 8; ++j) h[j] = f2b(r[j]);
        *(u16x8*)q = h;
    }
}

// ---------------- launch ----------------

extern "C" void kernel_launch(void* const* d_in, const int* in_sizes, int n_in,
                              void* d_out, int out_size, void* d_ws, size_t ws_size,
                              hipStream_t stream) {
    const float* x    = (const float*)d_in[0];
    const void*  eidx = d_in[1];
    const float* Wl0 = (const float*)d_in[2];
    const float* bl0 = (const float*)d_in[3];
    const float* Wr0 = (const float*)d_in[4];
    const float* Wl1 = (const float*)d_in[5];
    const float* bl1 = (const float*)d_in[6];
    const float* Wr1 = (const float*)d_in[7];
    const float* Wl2 = (const float*)d_in[8];
    const float* bl2 = (const float*)d_in[9];
    const float* Wr2 = (const float*)d_in[10];
    float* outF = (float*)d_out;
    unsigned short* preB = (unsigned short*)d_out;  // bf16 preact scratch (layers 1-2)

    char* ws = (char*)d_ws;
    size_t o = 0;
    auto alloc = [&](size_t bytes) { void* p = ws + o; o += (bytes + 255) & ~(size_t)255; return p; };

    // Concat activation planes: Cat1 [M][512] (agg256|feat256), Cat2 [M][1024]
    unsigned short* Cat1 = (unsigned short*)alloc((size_t)M_PAD * 512 * 2);
    unsigned short* Cat2 = (unsigned short*)alloc((size_t)M_PAD * 1024 * 2);

    unsigned short* Wcat0 = (unsigned short*)alloc(512 * 512 * 2);
    unsigned short* Wcat1 = (unsigned short*)alloc(512 * 1024 * 2);
    unsigned short* Wcat2 = (unsigned short*)alloc(512 * 1024 * 2);

    // counts/cursor MUST be one contiguous block (R2/R3 lesson).
    int* counts   = (int*)alloc((size_t)2 * N_NODES * 4);
    int* cursor   = counts + N_NODES;
    int* offsets  = (int*)alloc((size_t)(N_NODES + 1) * 4);
    int* edge_src = (int*)alloc((size_t)N_EDGES * 4);
    int* flag     = (int*)alloc(256);

    // ---- CSR build ----
    zero_detect_kernel<<<(2 * N_NODES + 255) / 256, 256, 0, stream>>>(
        counts, 2 * N_NODES, (const int*)eidx, flag);
    hist_kernel<<<(N_EDGES + 255) / 256, 256, 0, stream>>>(eidx, flag, counts);
    scan_kernel<<<1, 1024, 0, stream>>>(counts, offsets);
    fill_kernel<<<(N_EDGES + 255) / 256, 256, 0, stream>>>(eidx, flag, offsets, cursor, edge_src);

    // ---- conversions ----
    xconv_kernel<<<(M_PAD * 64 + 255) / 256, 256, 0, stream>>>(x, Cat1);
    wconv_kernel<<<512, 128, 0, stream>>>(Wl0, Wcat0, 256, 512, 0);
    wconv_kernel<<<512, 128, 0, stream>>>(Wr0, Wcat0, 256, 512, 256);
    wconv_kernel<<<512, 128, 0, stream>>>(Wl1, Wcat1, 512, 1024, 0);
    wconv_kernel<<<512, 128, 0, stream>>>(Wr1, Wcat1, 512, 1024, 512);
    wconv_kernel<<<512, 128, 0, stream>>>(Wl2, Wcat2, 512, 1024, 0);
    wconv_kernel<<<512, 128, 0, stream>>>(Wr2, Wcat2, 512, 1024, 512);

    const int ggrid = 2 * (M_PAD / 256);   // 392, 1D (swizzle computes bm/bn)
    const int nchunk = (N_NODES + 3) / 4;

    // layer 1 (feat 256): Cat1 = agg|x, K=512
    aggregate_kernel<4><<<nchunk, 256, 0, stream>>>(Cat1 + 256, offsets, edge_src, Cat1);
    gemm8_kernel<0><<<ggrid, 512, 0, stream>>>(Cat1, Wcat0, bl0, nullptr, preB, 512);
    norm_elu_kernel<0><<<nchunk, 256, 0, stream>>>(preB, nullptr, Cat2 + 512);

    // layer 2 (feat 512): Cat2 = agg|feat, K=1024
    aggregate_kernel<8><<<nchunk, 256, 0, stream>>>(Cat2 + 512, offsets, edge_src, Cat2);
    gemm8_kernel<0><<<ggrid, 512, 0, stream>>>(Cat2, Wcat1, bl1, nullptr, preB, 1024);
    norm_elu_kernel<0><<<nchunk, 256, 0, stream>>>(preB, nullptr, Cat2 + 512);

    // layer 3 (feat 512): final -> f32
    aggregate_kernel<8><<<nchunk, 256, 0, stream>>>(Cat2 + 512, offsets, edge_src, Cat2);
    gemm8_kernel<1><<<ggrid, 512, 0, stream>>>(Cat2, Wcat2, bl2, outF, nullptr, 1024);
    norm_elu_kernel<1><<<nchunk, 256, 0, stream>>>(outF, outF, nullptr);

    (void)in_sizes; (void)n_in; (void)out_size; (void)ws_size;
}

// Round 18
// 763.768 us; speedup vs baseline: 1.4187x; 1.0499x over previous
//
#include <hip/hip_runtime.h>
#include <math.h>

#define N_NODES 50000
#define M_PAD   50048   // 391 * 128
#define N_EDGES 800000
#define HID 512

typedef short bf16x8 __attribute__((ext_vector_type(8)));
typedef float f32x4  __attribute__((ext_vector_type(4)));
typedef unsigned short u16x4 __attribute__((ext_vector_type(4)));
typedef unsigned short u16x8 __attribute__((ext_vector_type(8)));

__device__ inline float b2f(unsigned short u) {
    union { unsigned int i; float f; } v; v.i = ((unsigned int)u) << 16; return v.f;
}
__device__ inline unsigned short f2b(float f) {
    union { float f; unsigned int i; } v; v.f = f;
    unsigned int r = v.i + 0x7FFFu + ((v.i >> 16) & 1u);
    return (unsigned short)(r >> 16);
}

// ---------------- CSR build ----------------

__global__ void zero_detect_kernel(int* __restrict__ p, int n,
                                   const int* __restrict__ e, int* __restrict__ flag) {
    int i = blockIdx.x * blockDim.x + threadIdx.x;
    if (i < n) p[i] = 0;
    if (blockIdx.x == 0 && threadIdx.x == 0) {
        int is64 = 1;
        for (int k = 0; k < 16; ++k)
            if (e[2 * k + 1] != 0) is64 = 0;
        *flag = is64;
    }
}

__global__ void hist_kernel(const void* __restrict__ eidx, const int* __restrict__ flag,
                            int* __restrict__ counts) {
    int e = blockIdx.x * blockDim.x + threadIdx.x;
    if (e >= N_EDGES) return;
    int is64 = *flag;
    int d;
    if (is64) d = (int)((const long long*)eidx)[N_EDGES + e];
    else      d = ((const int*)eidx)[N_EDGES + e];
    atomicAdd(&counts[d], 1);
}

__global__ __launch_bounds__(1024) void scan_kernel(const int* __restrict__ counts,
                                                    int* __restrict__ offsets) {
    __shared__ int sums[1024];
    int t = threadIdx.x;
    const int CH = (N_NODES + 1023) / 1024;  // 49
    int lo = t * CH;
    int hi = min(lo + CH, N_NODES);
    int s = 0;
    for (int i = lo; i < hi; ++i) s += counts[i];
    sums[t] = s;
    __syncthreads();
    for (int off = 1; off < 1024; off <<= 1) {
        int v = 0;
        if (t >= off) v = sums[t - off];
        __syncthreads();
        sums[t] += v;
        __syncthreads();
    }
    int excl = (t == 0) ? 0 : sums[t - 1];
    for (int i = lo; i < hi; ++i) { offsets[i] = excl; excl += counts[i]; }
    if (t == 1023) offsets[N_NODES] = excl;
}

__global__ void fill_kernel(const void* __restrict__ eidx, const int* __restrict__ flag,
                            const int* __restrict__ offsets, int* __restrict__ cursor,
                            int* __restrict__ edge_src) {
    int e = blockIdx.x * blockDim.x + threadIdx.x;
    if (e >= N_EDGES) return;
    int is64 = *flag;
    int s, d;
    if (is64) {
        const long long* p = (const long long*)eidx;
        s = (int)p[e];
        d = (int)p[N_EDGES + e];
    } else {
        const int* p = (const int*)eidx;
        s = p[e];
        d = p[N_EDGES + e];
    }
    int pos = atomicAdd(&cursor[d], 1);
    edge_src[offsets[d] + pos] = s;
}

// ---------------- conversions ----------------

// x (f32 [N,256]) -> bf16 into feat-half of Cat1 ([M][512], cols 256..512)
__global__ __launch_bounds__(256) void xconv_kernel(const float* __restrict__ x,
                                                    unsigned short* __restrict__ cat1) {
    int id = blockIdx.x * 256 + threadIdx.x;
    if (id >= M_PAD * 64) return;
    int row = id >> 6;
    int c = (id & 63) * 4;
    float4 v = make_float4(0.f, 0.f, 0.f, 0.f);
    if (row < N_NODES) v = *(const float4*)(x + (size_t)row * 256 + c);
    ushort4 h;
    h.x = f2b(v.x); h.y = f2b(v.y); h.z = f2b(v.z); h.w = f2b(v.w);
    *(ushort4*)(cat1 + (size_t)row * 512 + 256 + c) = h;
}

// All 6 weight transposes in ONE launch via LDS 64x64 tile transpose.
// Old version read W at 2KB thread-stride (16x overfetch) + scattered 2B
// writes; this one does coalesced 128B reads and 32B-aligned u16x8 writes.
// grid (8, 8, 6): (k-tile, n-tile, which-W); early-out for K=256 weights.
__global__ __launch_bounds__(256) void wconv_all_kernel(
    const float* __restrict__ Wl0, const float* __restrict__ Wr0,
    const float* __restrict__ Wl1, const float* __restrict__ Wr1,
    const float* __restrict__ Wl2, const float* __restrict__ Wr2,
    unsigned short* __restrict__ Wcat0, unsigned short* __restrict__ Wcat1,
    unsigned short* __restrict__ Wcat2) {
    const int z = blockIdx.z;
    const float* W = (z == 0) ? Wl0 : (z == 1) ? Wr0 : (z == 2) ? Wl1
                   : (z == 3) ? Wr1 : (z == 4) ? Wl2 : Wr2;
    unsigned short* T = (z < 2) ? Wcat0 : (z < 4) ? Wcat1 : Wcat2;
    const int K    = (z < 2) ? 256 : 512;
    const int ktot = (z < 2) ? 512 : 1024;
    const int off  = (z & 1) ? K : 0;

    const int k0 = blockIdx.x * 64;
    if (k0 >= K) return;
    const int n0 = blockIdx.y * 64;

    __shared__ float tile[64][65];
    const int r   = threadIdx.x >> 2;        // 0..63
    const int c16 = (threadIdx.x & 3) * 16;  // 0,16,32,48
#pragma unroll
    for (int j = 0; j < 16; j += 4) {
        float4 v = *(const float4*)(W + (size_t)(k0 + r) * HID + n0 + c16 + j);
        tile[r][c16 + j + 0] = v.x;
        tile[r][c16 + j + 1] = v.y;
        tile[r][c16 + j + 2] = v.z;
        tile[r][c16 + j + 3] = v.w;
    }
    __syncthreads();

    const int nl = threadIdx.x >> 2;         // 0..63 (output row within n-tile)
    const int kq = (threadIdx.x & 3) * 16;   // 0,16,32,48
    u16x8 h0, h1;
#pragma unroll
    for (int j = 0; j < 8; ++j) {
        h0[j] = f2b(tile[kq + j][nl]);
        h1[j] = f2b(tile[kq + 8 + j][nl]);
    }
    unsigned short* dst = T + (size_t)(n0 + nl) * ktot + off + k0 + kq;
    *(u16x8*)dst = h0;
    *(u16x8*)(dst + 8) = h1;
}

// ---------------- aggregate: wave-per-node row-gather, 4 chains (R13-verified) ----------------

template <int EPL>
__global__ __launch_bounds__(256) void aggregate_kernel(const unsigned short* __restrict__ Fh,
                                                        const int* __restrict__ off,
                                                        const int* __restrict__ esrc,
                                                        unsigned short* __restrict__ Ah) {
    const int STRIDE = 2 * EPL * 64;
    const int wid = threadIdx.x >> 6;
    const int lane = threadIdx.x & 63;
    const int node = blockIdx.x * 4 + wid;
    if (node >= N_NODES) return;
    const int beg = off[node], end = off[node + 1];
    const int deg = end - beg;
    const int lb = lane * EPL;
    using VecT = typename std::conditional<EPL == 8, u16x8, u16x4>::type;

    float a0[EPL], a1[EPL], a2[EPL], a3[EPL];
#pragma unroll
    for (int j = 0; j < EPL; ++j) { a0[j] = 0.f; a1[j] = 0.f; a2[j] = 0.f; a3[j] = 0.f; }

    int idxv = 0;
#define ACC(ARR, S)                                                         \
    {                                                                       \
        VecT v_ = *(const VecT*)(Fh + (size_t)(S) * STRIDE + lb);           \
        _Pragma("unroll")                                                   \
        for (int j_ = 0; j_ < EPL; ++j_) ARR[j_] += b2f(v_[j_]);            \
    }
    for (int i = 0; i < deg; i += 4) {
        const int b = i & 63;
        if (b == 0) idxv = (beg + i + lane < end) ? esrc[beg + i + lane] : 0;
        const int s0 = __shfl(idxv, b);
        const int s1 = __shfl(idxv, b + 1);
        const int s2 = __shfl(idxv, b + 2);
        const int s3 = __shfl(idxv, b + 3);
        ACC(a0, s0);
        if (i + 1 < deg) ACC(a1, s1);
        if (i + 2 < deg) ACC(a2, s2);
        if (i + 3 < deg) ACC(a3, s3);
    }
#undef ACC
    unsigned short* op = Ah + (size_t)node * STRIDE + lb;
    VecT h;
#pragma unroll
    for (int j = 0; j < EPL; ++j) h[j] = f2b(a0[j] + a1[j] + a2[j] + a3[j]);
    __builtin_nontemporal_store(h, (VecT*)op);
}

// ---------------- concat-K MFMA GEMM: 128x256 tile, 8 waves, 2-phase dbuf ----------------
// R13-verified (782 blocks -> good CU balance; gemm8's 392-block 256-tile was
// load-imbalance-neutral at this skinny-N geometry).  Bijective XCD-pair swizzle.

template <int FINAL>
__global__ __launch_bounds__(512, 2) void gemm_mfma_kernel(
    const unsigned short* __restrict__ A, const unsigned short* __restrict__ B,
    const float* __restrict__ bias, float* __restrict__ outF,
    unsigned short* __restrict__ pre, int K) {
    __shared__ unsigned short S[2 * 12288];  // u16 elems: 2 x (4096 A + 8192 B)
    const int T = gridDim.x;          // 782
    const int q = T >> 3, r = T & 7;
    const int xcd = blockIdx.x & 7;
    const int n0 = blockIdx.x >> 3;
    const int g = xcd * q + min(xcd, r) + n0;
    const int bm = (g >> 1) * 128;
    const int bn = (g & 1) * 256;

    const int tid = threadIdx.x;
    const int l = tid & 63;
    const int w = tid >> 6;          // 0..7
    const int wr = (w >> 2) * 64;    // 2 row-waves
    const int wc = (w & 3) * 64;     // 4 col-waves

    const int se = (tid >> 2) * 32 + (tid & 3) * 8;
    const unsigned short* gA  = A + (size_t)(bm + (tid >> 2)) * K + (tid & 3) * 8;
    const unsigned short* gB0 = B + (size_t)(bn + (tid >> 2)) * K + (tid & 3) * 8;
    const unsigned short* gB1 = B + (size_t)(bn + 128 + (tid >> 2)) * K + (tid & 3) * 8;

    f32x4 acc[4][4];
#pragma unroll
    for (int m = 0; m < 4; ++m)
#pragma unroll
        for (int nn = 0; nn < 4; ++nn) acc[m][nn] = (f32x4){0.f, 0.f, 0.f, 0.f};

    const int aoff = (wr + (l & 15)) * 32 + (l >> 4) * 8;
    const int woff = 4096 + (wc + (l & 15)) * 32 + (l >> 4) * 8;
    const int ktiles = K >> 5;

    auto STAGE = [&](int buf, int kt) {
        unsigned short* lb = &S[buf * 12288];
        __builtin_amdgcn_global_load_lds(
            (const __attribute__((address_space(1))) void*)(gA + kt * 32),
            (__attribute__((address_space(3))) void*)(lb + se), 16, 0, 0);
        __builtin_amdgcn_global_load_lds(
            (const __attribute__((address_space(1))) void*)(gB0 + kt * 32),
            (__attribute__((address_space(3))) void*)(lb + 4096 + se), 16, 0, 0);
        __builtin_amdgcn_global_load_lds(
            (const __attribute__((address_space(1))) void*)(gB1 + kt * 32),
            (__attribute__((address_space(3))) void*)(lb + 8192 + se), 16, 0, 0);
    };

    STAGE(0, 0);
    __syncthreads();

    for (int kt = 0; kt < ktiles; ++kt) {
        if (kt + 1 < ktiles) STAGE((kt + 1) & 1, kt + 1);  // prefetch next
        const int sb = (kt & 1) * 12288;

        bf16x8 af[4], wf[4];
#pragma unroll
        for (int m = 0; m < 4; ++m)
            af[m] = *(const bf16x8*)&S[sb + aoff + m * 512];
#pragma unroll
        for (int nn = 0; nn < 4; ++nn)
            wf[nn] = *(const bf16x8*)&S[sb + woff + nn * 512];
#pragma unroll
        for (int m = 0; m < 4; ++m)
#pragma unroll
            for (int nn = 0; nn < 4; ++nn)
                acc[m][nn] = __builtin_amdgcn_mfma_f32_16x16x32_bf16(af[m], wf[nn], acc[m][nn], 0, 0, 0);
        __syncthreads();
    }

    const int r0 = bm + wr + (l >> 4) * 4;
    const int c0 = bn + wc + (l & 15);
#pragma unroll
    for (int nn = 0; nn < 4; ++nn) {
        const float bv = bias[c0 + nn * 16];
#pragma unroll
        for (int m = 0; m < 4; ++m) {
#pragma unroll
            for (int j = 0; j < 4; ++j) {
                int gr = r0 + m * 16 + j;
                if (gr < N_NODES) {
                    float val = acc[m][nn][j] + bv;
                    if constexpr (FINAL)
                        outF[(size_t)gr * HID + c0 + nn * 16] = val;
                    else
                        pre[(size_t)gr * HID + c0 + nn * 16] = f2b(val);
                }
            }
        }
    }
}

// ---------------- row L2-normalize + ELU (wave-per-row) ----------------

template <int FINAL>
__global__ __launch_bounds__(256) void norm_elu_kernel(const void* __restrict__ inp,
                                                       float* __restrict__ outF,
                                                       unsigned short* __restrict__ Fh) {
    const int wid = threadIdx.x >> 6;
    const int lane = threadIdx.x & 63;
    const int row = blockIdx.x * 4 + wid;
    if (row >= N_NODES) return;
    float r[8];
    if constexpr (FINAL) {
        const float* p = (const float*)inp + (size_t)row * HID + lane * 8;
        float4 v0 = *(const float4*)p;
        float4 v1 = *(const float4*)(p + 4);
        r[0] = v0.x; r[1] = v0.y; r[2] = v0.z; r[3] = v0.w;
        r[4] = v1.x; r[5] = v1.y; r[6] = v1.z; r[7] = v1.w;
    } else {
        const unsigned short* p = (const unsigned short*)inp + (size_t)row * HID + lane * 8;
        u16x8 v = *(const u16x8*)p;
#pragma unroll
        for (int j = 0; j < 8; ++j) r[j] = b2f(v[j]);
    }
    float ss = 0.f;
#pragma unroll
    for (int j = 0; j < 8; ++j) ss += r[j] * r[j];
#pragma unroll
    for (int o = 32; o > 0; o >>= 1) ss += __shfl_xor(ss, o);
    float inv = 1.f / fmaxf(sqrtf(ss), 1e-12f);
#pragma unroll
    for (int j = 0; j < 8; ++j) {
        r[j] *= inv;
        r[j] = r[j] > 0.f ? r[j] : expm1f(r[j]);
    }
    if constexpr (FINAL) {
        float* q = outF + (size_t)row * HID + lane * 8;
        *(float4*)q = make_float4(r[0], r[1], r[2], r[3]);
        *(float4*)(q + 4) = make_float4(r[4], r[5], r[6], r[7]);
    } else {
        unsigned short* q = Fh + (size_t)row * 1024 + lane * 8;
        u16x8 h;
#pragma unroll
        for (int j = 0; j < 8; ++j) h[j] = f2b(r[j]);
        *(u16x8*)q = h;
    }
}

// ---------------- launch ----------------

extern "C" void kernel_launch(void* const* d_in, const int* in_sizes, int n_in,
                              void* d_out, int out_size, void* d_ws, size_t ws_size,
                              hipStream_t stream) {
    const float* x    = (const float*)d_in[0];
    const void*  eidx = d_in[1];
    const float* Wl0 = (const float*)d_in[2];
    const float* bl0 = (const float*)d_in[3];
    const float* Wr0 = (const float*)d_in[4];
    const float* Wl1 = (const float*)d_in[5];
    const float* bl1 = (const float*)d_in[6];
    const float* Wr1 = (const float*)d_in[7];
    const float* Wl2 = (const float*)d_in[8];
    const float* bl2 = (const float*)d_in[9];
    const float* Wr2 = (const float*)d_in[10];
    float* outF = (float*)d_out;
    unsigned short* preB = (unsigned short*)d_out;  // bf16 preact scratch (layers 1-2)

    char* ws = (char*)d_ws;
    size_t o = 0;
    auto alloc = [&](size_t bytes) { void* p = ws + o; o += (bytes + 255) & ~(size_t)255; return p; };

    // Concat activation planes: Cat1 [M][512] (agg256|feat256), Cat2 [M][1024]
    unsigned short* Cat1 = (unsigned short*)alloc((size_t)M_PAD * 512 * 2);
    unsigned short* Cat2 = (unsigned short*)alloc((size_t)M_PAD * 1024 * 2);

    unsigned short* Wcat0 = (unsigned short*)alloc(512 * 512 * 2);
    unsigned short* Wcat1 = (unsigned short*)alloc(512 * 1024 * 2);
    unsigned short* Wcat2 = (unsigned short*)alloc(512 * 1024 * 2);

    // counts/cursor MUST be one contiguous block (R2/R3 lesson).
    int* counts   = (int*)alloc((size_t)2 * N_NODES * 4);
    int* cursor   = counts + N_NODES;
    int* offsets  = (int*)alloc((size_t)(N_NODES + 1) * 4);
    int* edge_src = (int*)alloc((size_t)N_EDGES * 4);
    int* flag     = (int*)alloc(256);

    // ---- CSR build ----
    zero_detect_kernel<<<(2 * N_NODES + 255) / 256, 256, 0, stream>>>(
        counts, 2 * N_NODES, (const int*)eidx, flag);
    hist_kernel<<<(N_EDGES + 255) / 256, 256, 0, stream>>>(eidx, flag, counts);
    scan_kernel<<<1, 1024, 0, stream>>>(counts, offsets);
    fill_kernel<<<(N_EDGES + 255) / 256, 256, 0, stream>>>(eidx, flag, offsets, cursor, edge_src);

    // ---- conversions ----
    xconv_kernel<<<(M_PAD * 64 + 255) / 256, 256, 0, stream>>>(x, Cat1);
    {
        dim3 wgrid(8, 8, 6);
        wconv_all_kernel<<<wgrid, 256, 0, stream>>>(Wl0, Wr0, Wl1, Wr1, Wl2, Wr2,
                                                    Wcat0, Wcat1, Wcat2);
    }

    const int ggrid = 2 * (M_PAD / 128);   // 782, 1D (swizzle computes bm/bn)
    const int nchunk = (N_NODES + 3) / 4;

    // layer 1 (feat 256): Cat1 = agg|x, K=512
    aggregate_kernel<4><<<nchunk, 256, 0, stream>>>(Cat1 + 256, offsets, edge_src, Cat1);
    gemm_mfma_kernel<0><<<ggrid, 512, 0, stream>>>(Cat1, Wcat0, bl0, nullptr, preB, 512);
    norm_elu_kernel<0><<<nchunk, 256, 0, stream>>>(preB, nullptr, Cat2 + 512);

    // layer 2 (feat 512): Cat2 = agg|feat, K=1024
    aggregate_kernel<8><<<nchunk, 256, 0, stream>>>(Cat2 + 512, offsets, edge_src, Cat2);
    gemm_mfma_kernel<0><<<ggrid, 512, 0, stream>>>(Cat2, Wcat1, bl1, nullptr, preB, 1024);
    norm_elu_kernel<0><<<nchunk, 256, 0, stream>>>(preB, nullptr, Cat2 + 512);

    // layer 3 (feat 512): final -> f32
    aggregate_kernel<8><<<nchunk, 256, 0, stream>>>(Cat2 + 512, offsets, edge_src, Cat2);
    gemm_mfma_kernel<1><<<ggrid, 512, 0, stream>>>(Cat2, Wcat2, bl2, outF, nullptr, 1024);
    norm_elu_kernel<1><<<nchunk, 256, 0, stream>>>(outF, outF, nullptr);

    (void)in_sizes; (void)n_in; (void)out_size; (void)ws_size;
}